// Round 9
// baseline (451.238 us; speedup 1.0000x reference)
//
#include <hip/hip_runtime.h>

typedef unsigned short u16;
typedef unsigned int u32;
typedef __attribute__((ext_vector_type(8))) short short8v;   // 8 bf16 MFMA frag
typedef __attribute__((ext_vector_type(4))) float f32x4;
typedef __attribute__((ext_vector_type(2))) float f32x2;
typedef __attribute__((ext_vector_type(4))) unsigned int uint4v;
typedef __attribute__((ext_vector_type(2))) unsigned int uint2v;
typedef __attribute__((ext_vector_type(8))) unsigned short us8;
typedef __attribute__((ext_vector_type(4))) unsigned short us4;

#define B_   4
#define S_   19950
#define C_   256
#define NH   8
#define DH   32
#define BS_  (B_*S_)          // 79800

#define BM 128
#define BN 128

__device__ __forceinline__ float bf2f(u16 u){ u32 x=((u32)u)<<16; float f; __builtin_memcpy(&f,&x,4); return f; }
__device__ __forceinline__ u16 f2bf(float f){ u32 x; __builtin_memcpy(&x,&f,4); x += 0x7fffu + ((x>>16)&1u); return (u16)(x>>16); }
__device__ __forceinline__ u32 cvtpk(float a, float b){ u32 r; asm("v_cvt_pk_bf16_f32 %0, %1, %2" : "=v"(r) : "v"(a), "v"(b)); return r; }
__device__ __forceinline__ f32x2 pkfma(f32x2 a, f32x2 b, f32x2 d){
  asm("v_pk_fma_f32 %0, %1, %2, %0" : "+v"(d) : "v"(a), "v"(b)); return d;
}
__device__ __forceinline__ f32x2 unpk(u32 p){
  uint2v u; u.x = p<<16; u.y = p & 0xffff0000u; return __builtin_bit_cast(f32x2, u);
}

// ============ Persistent-panel MFMA GEMM: one block per 128-row M-panel ============
// A (128 x 256) converted to bf16 ONCE into LDS, reused across all N-tiles/k-steps.
// B (128 x 64 bf16 per step) double-buffered, reg-staged with issue-early loads.
// LDS: A 64 KB + B 2x16 KB = 96 KB -> 1 block/CU.
// MODE 0: A=value f32 -> v bf16 permuted (b,h,s,dh);  MODE 1: A=query f32 -> soff+softmax sattn
// MODE 2: A=tmp bf16 (DMA burst) -> out f32.
template<int MODE>
__device__ __forceinline__ void proj_core(int y, u32* smem, const void* __restrict__ Aany,
    const float* __restrict__ Wmain, const float* __restrict__ Wattn,
    const float* __restrict__ bmain, const float* __restrict__ battn,
    void* __restrict__ out0, u16* __restrict__ out1)
{
  u32* Abf = smem;           // [128 rows][128 u32] = 256 bf16/row, 16B-chunk XOR swizzle
  u32* Bd  = smem + 16384;   // [2][128 rows][32 u32]

  const int tid = threadIdx.x;
  const int lane = tid & 63, wid = tid >> 6;
  const int wm = wid >> 1, wn = wid & 1;
  const int ln15 = lane & 15, ln4 = lane >> 4;
  const int m0 = y * BM;

  // ---- B staging lambdas (coalesced: chunk idx = i*256+tid over 128x16 f32x4) ----
  auto loadB = [&](int x, int k0, f32x4* rb){
    #pragma unroll
    for (int i=0;i<8;++i){
      const int idx = i*256 + tid;
      const int row = idx >> 4, c = idx & 15;
      const float* src;
      if constexpr (MODE==1) {
        const int n = x*BN + row;
        src = (n < 192) ? (Wmain + (size_t)n*C_) : (Wattn + (size_t)(min(n,287)-192)*C_);
      } else {
        src = Wmain + (size_t)(x*BN + row)*C_;
      }
      rb[i] = *(const f32x4*)(src + k0 + c*4);
    }
  };
  auto writeB = [&](int buf, const f32x4* rb){
    #pragma unroll
    for (int i=0;i<8;++i){
      const int idx = i*256 + tid;
      const int row = idx >> 4, c = idx & 15;
      const int cc = c >> 1;
      uint2v pk; pk.x = cvtpk(rb[i].x, rb[i].y); pk.y = cvtpk(rb[i].z, rb[i].w);
      *(uint2v*)&Bd[buf*4096 + row*32 + ((cc ^ (row&7))<<2) + (c&1)*2] = pk;
    }
  };

  // ---- issue first B loads, then stage A (B loads in flight under A burst) ----
  f32x4 rb0[8];
  loadB(0, 0, rb0);

  if constexpr (MODE==2) {
    // A already bf16: async DMA burst, linear dest, inverse-swizzled source
    const u16* Ab = (const u16*)Aany;
    #pragma unroll
    for (int i=0;i<16;++i){
      const int line = i*256 + tid;            // 16B line, 4096 total
      const int row = line >> 5, c = line & 31;
      const int rg = min(m0 + row, BS_-1);
      __builtin_amdgcn_global_load_lds(Ab + (size_t)rg*C_ + ((c ^ (row&7))<<3),
          (u16*)&Abf[(i*256 + wid*64)*4], 16, 0, 0);
    }
  } else {
    // A f32 -> cvt bf16 -> swizzled ds_write (coalesced chunk idx)
    const float* Af = (const float*)Aany;
    #pragma unroll
    for (int i=0;i<32;++i){
      const int idx = i*256 + tid;             // f32x4 chunk, 128x64 total
      const int row = idx >> 6, c = idx & 63;
      const int rg = min(m0 + row, BS_-1);
      const f32x4 vv = *(const f32x4*)(Af + (size_t)rg*C_ + c*4);
      const int cc = c >> 1;
      uint2v pk; pk.x = cvtpk(vv.x, vv.y); pk.y = cvtpk(vv.z, vv.w);
      *(uint2v*)&Abf[row*128 + ((cc ^ (row&7))<<2) + (c&1)*2] = pk;
    }
  }
  writeB(0, rb0);
  __syncthreads();   // drains A (DMA vmcnt or ds_writes) + B writes

  f32x4 acc[4][4];
  #pragma unroll
  for (int i=0;i<4;++i){
    #pragma unroll
    for (int j=0;j<4;++j) acc[i][j] = (f32x4){0.f,0.f,0.f,0.f};
  }

  constexpr int NS = (MODE==1) ? 12 : 8;   // (x-tiles) x (4 k-steps)
  for (int s=0; s<NS; ++s) {
    const int cur = s & 1;
    const int kq = s & 3;
    f32x4 rbn[8];
    if (s+1 < NS) loadB((s+1)>>2, ((s+1)&3)*64, rbn);   // issue-early for next step

    // ---- compute k-chunk kq from resident A + Bd[cur] ----
    #pragma unroll
    for (int ks=0; ks<2; ++ks) {
      short8v af[4], bfr[4];
      #pragma unroll
      for (int mi=0;mi<4;++mi){
        const int row = wm*64 + mi*16 + ln15;
        const int ca = kq*8 + ks*4 + ln4;
        af[mi] = *(const short8v*)&Abf[row*128 + ((ca ^ (row&7))<<2)];
      }
      #pragma unroll
      for (int ni=0;ni<4;++ni){
        const int row = wn*64 + ni*16 + ln15;
        const int cb = ks*4 + ln4;
        bfr[ni] = *(const short8v*)&Bd[cur*4096 + row*32 + ((cb ^ (row&7))<<2)];
      }
      #pragma unroll
      for (int mi=0;mi<4;++mi){
        #pragma unroll
        for (int ni=0;ni<4;++ni)
          acc[mi][ni] = __builtin_amdgcn_mfma_f32_16x16x32_bf16(af[mi], bfr[ni], acc[mi][ni], 0, 0, 0);
      }
    }

    // ---- epilogue for finished x-tile (validated rounds 2/4/8) ----
    if (kq == 3) {
      const int n0 = (s>>2) * BN;
      #pragma unroll
      for (int mi=0;mi<4;++mi){
        #pragma unroll
        for (int ni=0;ni<4;++ni){
          const int n = n0 + wn*64 + ni*16 + ln15;
          if (MODE==1 && n >= 288) continue;
          float bias;
          if constexpr (MODE==1) bias = (n < 192) ? bmain[n] : battn[n-192];
          else                   bias = bmain[n];
          if (MODE==1 && n >= 192) {
            #pragma unroll
            for (int j=0;j<4;++j){
              const int m = m0 + wm*64 + mi*16 + ln4*4 + j;
              const float vv = acc[mi][ni][j] + bias;
              float mx = vv;
              mx = fmaxf(mx, __shfl_xor(mx, 1));
              mx = fmaxf(mx, __shfl_xor(mx, 2));
              const float e = __expf(vv - mx);
              float ssum = e;
              ssum += __shfl_xor(ssum, 1);
              ssum += __shfl_xor(ssum, 2);
              if (m < BS_) out1[(size_t)m*96 + (n-192)] = f2bf(e/ssum);
            }
          } else if (MODE==1) {
            u16* soff = (u16*)out0;
            #pragma unroll
            for (int j=0;j<4;++j){
              const int m = m0 + wm*64 + mi*16 + ln4*4 + j;
              if (m < BS_) soff[(size_t)m*192 + n] = f2bf(acc[mi][ni][j] + bias);
            }
          } else if (MODE==0) {
            u16* vout = (u16*)out0;
            const int h = n >> 5, dh = n & 31;
            #pragma unroll
            for (int j=0;j<4;++j){
              const int m = m0 + wm*64 + mi*16 + ln4*4 + j;
              if (m < BS_) {
                const int bq = m / S_, sq = m - bq*S_;
                vout[((size_t)(bq*NH+h)*S_ + sq)*DH + dh] = f2bf(acc[mi][ni][j] + bias);
              }
            }
          } else {
            float* outp = (float*)out0;
            #pragma unroll
            for (int j=0;j<4;++j){
              const int m = m0 + wm*64 + mi*16 + ln4*4 + j;
              if (m < BS_) outp[(size_t)m*C_ + n] = acc[mi][ni][j] + bias;
            }
          }
        }
      }
      #pragma unroll
      for (int i=0;i<4;++i){
        #pragma unroll
        for (int j=0;j<4;++j) acc[i][j] = (f32x4){0.f,0.f,0.f,0.f};
      }
    }

    if (s+1 < NS) writeB(cur^1, rbn);   // waits rbn; writes buffer not being read
    __syncthreads();
  }
}

// ---- FUSED projections: mode interleaved by blockIdx parity ----
__global__ __launch_bounds__(256) void k_projP(
    const void* __restrict__ value, const float* __restrict__ Wv,
    const float* __restrict__ bv, void* __restrict__ vout,
    const void* __restrict__ query, const float* __restrict__ Wo,
    const float* __restrict__ Wa, const float* __restrict__ bo,
    const float* __restrict__ ba, void* __restrict__ soff, u16* __restrict__ sattn)
{
  __shared__ u32 smem[24576];   // 96 KB
  const int g = blockIdx.x;
  if (g & 1) proj_core<1>(g>>1, smem, query, Wo, Wa, bo, ba, soff, sattn);
  else       proj_core<0>(g>>1, smem, value, Wv, nullptr, bv, nullptr, vout, nullptr);
}

__global__ __launch_bounds__(256) void k_gemm2P(const void* __restrict__ A,
    const float* __restrict__ W, const float* __restrict__ b, void* __restrict__ o)
{
  __shared__ u32 smem[24576];   // 96 KB
  proj_core<2>(blockIdx.x, smem, A, W, nullptr, b, nullptr, o, nullptr);
}

// ================= Sampler v3 (round-4/8 proven, 137 us): 8 ch/thread =================
#define NCH 312   // ceil(19950/64) chunks of 64 queries

__global__ __launch_bounds__(256) void k_sample3(const u16* __restrict__ v,
    const u16* __restrict__ soff, const u16* __restrict__ sattn,
    const float* __restrict__ refp, u16* __restrict__ tmp)
{
  const int g = blockIdx.x;
  const int xcd = g & 7, inner = g >> 3;      // inner in [0, 4*NCH)
  const int unit = inner / NCH;               // 0..3
  const int cidx = inner - unit*NCH;
  const int bh = xcd*4 + unit;                // 4 (b,h)-slices per XCD for L2 locality
  const int b = bh >> 3, h = bh & 7;
  const int dh0 = (threadIdx.x & 3) * 8;
  const int q = cidx*64 + (threadIdx.x >> 2);
  if (q >= S_) return;
  const size_t r = (size_t)b*S_ + q;
  const float refx = refp[r*2+0], refy = refp[r*2+1];
  const u16* vb = v + (size_t)bh * S_ * DH;

  const u16* sop = soff + r*192 + h*24;
  const u16* sap = sattn + r*96 + h*12;
  us8 so0 = *(const us8*)(sop);
  us8 so1 = *(const us8*)(sop + 8);
  us8 so2 = *(const us8*)(sop + 16);
  us4 sa0 = *(const us4*)(sap);
  us4 sa1 = *(const us4*)(sap + 4);
  us4 sa2 = *(const us4*)(sap + 8);
  u16 soarr[24]; u16 saarr[12];
  #pragma unroll
  for (int i=0;i<8;++i){ soarr[i]=so0[i]; soarr[8+i]=so1[i]; soarr[16+i]=so2[i]; }
  #pragma unroll
  for (int i=0;i<4;++i){ saarr[i]=sa0[i]; saarr[4+i]=sa1[i]; saarr[8+i]=sa2[i]; }

  f32x2 acc0 = (f32x2){0.f,0.f}, acc1 = acc0, acc2 = acc0, acc3 = acc0;
  const int WLs[3]={152,76,38}, HLs[3]={100,50,25}, STs[3]={0,15200,19000};
  #pragma unroll
  for (int l=0;l<3;++l) {
    const int Wl=WLs[l], Hl=HLs[l];
    const float rxl = refx*(float)Wl - 0.5f;   // ix = ref*W + off - 0.5 (normalizer folded)
    const float ryl = refy*(float)Hl - 0.5f;
    const u16* vbl = vb + (size_t)STs[l]*DH;
    #pragma unroll
    for (int p=0;p<4;++p) {
      const int idx = l*4 + p;
      const float ix = rxl + bf2f(soarr[2*idx+0]);
      const float iy = ryl + bf2f(soarr[2*idx+1]);
      const float aw = bf2f(saarr[idx]);
      const float x0f = floorf(ix), y0f = floorf(iy);
      const float wx1 = ix-x0f, wy1 = iy-y0f;
      const float wx0 = 1.f-wx1, wy0 = 1.f-wy1;
      const int x0 = (int)x0f, y0 = (int)y0f;
      #pragma unroll
      for (int dy=0; dy<2; ++dy) {
        const int yc = y0+dy;
        const bool vy = (yc>=0) && (yc<Hl);
        const int yi = min(max(yc,0),Hl-1);
        const float wyf = aw * (dy?wy1:wy0);
        #pragma unroll
        for (int dx=0; dx<2; ++dx) {
          const int xc = x0+dx;
          const bool vx = (xc>=0) && (xc<Wl);
          const int xi = min(max(xc,0),Wl-1);
          float w = wyf * (dx?wx1:wx0);
          if (!(vx && vy)) w = 0.f;
          f32x2 w2; w2.x = w; w2.y = w;
          const uint4v t = *(const uint4v*)(vbl + (size_t)(yi*Wl + xi)*DH + dh0);
          acc0 = pkfma(unpk(t.x), w2, acc0);
          acc1 = pkfma(unpk(t.y), w2, acc1);
          acc2 = pkfma(unpk(t.z), w2, acc2);
          acc3 = pkfma(unpk(t.w), w2, acc3);
        }
      }
    }
  }
  uint4v o;
  o.x = cvtpk(acc0.x, acc0.y); o.y = cvtpk(acc1.x, acc1.y);
  o.z = cvtpk(acc2.x, acc2.y); o.w = cvtpk(acc3.x, acc3.y);
  *(uint4v*)(tmp + r*C_ + (size_t)h*DH + dh0) = o;
}

extern "C" void kernel_launch(void* const* d_in, const int* in_sizes, int n_in,
                              void* d_out, int out_size, void* d_ws, size_t ws_size,
                              hipStream_t stream) {
  (void)in_sizes; (void)n_in; (void)out_size; (void)ws_size;
  const float* query = (const float*)d_in[0];
  const float* value = (const float*)d_in[1];
  const float* refp  = (const float*)d_in[4];
  const float* W_off = (const float*)d_in[5];
  const float* b_off = (const float*)d_in[6];
  const float* W_attn= (const float*)d_in[7];
  const float* b_attn= (const float*)d_in[8];
  const float* W_val = (const float*)d_in[9];
  const float* b_val = (const float*)d_in[10];
  const float* W_out = (const float*)d_in[11];
  const float* b_out = (const float*)d_in[12];
  float* out = (float*)d_out;

  char* ws = (char*)d_ws;
  constexpr size_t V_BYTES    = (size_t)BS_*C_*2;     // 40.9 MB: v bf16 (b,h,s,dh)
  constexpr size_t SOFF_BYTES = (size_t)BS_*192*2;    // 30.6 MB
  constexpr size_t SATTN_BYTES= (size_t)BS_*96*2;     // 15.3 MB
  u16* v     = (u16*)(ws);
  u16* soff  = (u16*)(ws + V_BYTES);
  u16* sattn = (u16*)(ws + V_BYTES + SOFF_BYTES);
  u16* tmp   = (u16*)(ws + V_BYTES + SOFF_BYTES + SATTN_BYTES);

  dim3 blk(256);
  hipLaunchKernelGGL(k_projP, dim3(2*624), blk, 0, stream,
                     (const void*)value, W_val, b_val, (void*)v,
                     (const void*)query, W_off, W_attn, b_off, b_attn,
                     (void*)soff, sattn);
  hipLaunchKernelGGL(k_sample3, dim3(8*4*NCH), blk, 0, stream, v, soff, sattn, refp, tmp);
  hipLaunchKernelGGL(k_gemm2P, dim3(624), blk, 0, stream,
                     (const void*)tmp, W_out, b_out, (void*)out);
}